// Round 6
// baseline (135.237 us; speedup 1.0000x reference)
//
#include <hip/hip_runtime.h>

typedef unsigned short u16;
typedef unsigned int   u32;
typedef __attribute__((ext_vector_type(4))) float f32x4;
typedef __attribute__((ext_vector_type(8))) short bf16x8;

// ---------- compile-time Cl(3,0,1) tables ----------
constexpr int pcf(int x){ int c=0; while(x){ c += x&1; x>>=1; } return c; }
constexpr int signexp(int a,int b){ int s=0; a>>=1; while(a){ s += pcf(a&b); a>>=1; } return s&1; }
constexpr float sgnf(int a,int b){ return signexp(a,b) ? -1.0f : 1.0f; }
constexpr float sDf(int a){ return sgnf(a, a^15); }

struct Tbl {
  float gp[16][16];   // g1[a]*g2[b] -> out[a^b], 0 if e0 overlap
  float jn[16][16];   // j1[a]*j2[b] -> out[a&b], 0 unless a|b==15
};
constexpr Tbl make_tbl(){
  Tbl t{};
  for(int a=0;a<16;a++){
    for(int b=0;b<16;b++){
      t.gp[a][b] = (a & b & 1) ? 0.0f : sgnf(a,b);
      t.jn[a][b] = ((a|b)==15) ? sDf(a)*sDf(b)*sDf(a&b)*sgnf(a^15,b^15) : 0.0f;
    }
  }
  return t;
}
constexpr Tbl TBL = make_tbl();
constexpr int PC[16] = {0,1,1,2,1,2,2,3,1,2,2,3,2,3,3,4};

// y-planes grouped by grade (pc). Verified weight-index formula:
// out[y] += w[pc(y)]*x[y]  and for odd y: out[y] += w[4+pc(y)]*x[y^1]
constexpr int GRADE_Y[5][6] = {{0,0,0,0,0,0},{1,2,4,8,0,0},{3,5,6,9,10,12},{7,11,13,14,0,0},{15,0,0,0,0,0}};
constexpr int GRADE_N[5] = {1,4,6,4,1};

__device__ __forceinline__ u16 f2bf(float f){
  union { float f; unsigned u; } v; v.f = f;
  unsigned r = v.u + 0x7fffu + ((v.u >> 16) & 1u);   // RNE
  return (u16)(r >> 16);
}

// raw barrier: per-wave LDS drain + s_barrier, NO vmcnt drain (prefetch
// loads stay in flight across it). "memory" clobber stops LDS caching/CSE.
#define BARRIER() do {                                          \
  asm volatile("s_waitcnt lgkmcnt(0)" ::: "memory");            \
  __builtin_amdgcn_sched_barrier(0);                            \
  __builtin_amdgcn_s_barrier();                                 \
  __builtin_amdgcn_sched_barrier(0);                            \
} while (0)

// =====================================================================
// Kernel: weights fp32 -> bf16 B-fragments
// wb offset: ((t*9+b)*8 + nt*2 + kt)*512 + lane*8 + j
//   nt = c>>4, lane = 16*((i>>3)&3) + (c&15), kt = i>>5, j = i&7
// =====================================================================
__global__ __launch_bounds__(256) void k_wb(const float* __restrict__ wg1,
                                            const float* __restrict__ wg2,
                                            const float* __restrict__ wj1,
                                            const float* __restrict__ wj2,
                                            u16* __restrict__ wb)
{
  const int e = blockIdx.x*256 + threadIdx.x;      // 0 .. 147455
  const int t   = e / 36864;                        // tensor (wave-uniform)
  const int rem = e % 36864;                        // c*576 + i*9 + b
  const int c = rem / 576, r2 = rem % 576, i = r2 / 9, b = r2 % 9;
  const float* wp = (t < 2) ? (t ? wg2 : wg1) : ((t == 2) ? wj1 : wj2);
  const float v = wp[rem];
  const int dst = ((t*9 + b)*8 + (c>>4)*2 + (i>>5))*512
                + (16*((i>>3)&3) + (c&15))*8 + (i&7);
  wb[dst] = f2bf(v);
}

// =====================================================================
// Persistent pipelined kernel: tpb tiles per block, register prefetch,
// raw barriers (3/iter) keep next-tile loads in flight across phases.
// 512 thr = 8 waves: pair = w>>2 (0:gp 1:jn), nt = w&3.
// __launch_bounds__(512, 2): 2 waves/EU min -> 256-VGPR budget. This is
// the knob round 5 got wrong (amdgpu_waves_per_eu was ignored -> cap 128
// -> scratch spill -> +300 MB HBM traffic).
// =====================================================================
__global__ __launch_bounds__(512, 2)
void k_pipe(const float* __restrict__ x, const u16* __restrict__ wb,
            const float* __restrict__ ref, float* __restrict__ out,
            int tpb)
{
  __shared__ __align__(16) u16 F[16384];     // 32 KB frag buffer / scratch

  const int t = threadIdx.x, w = t >> 6, l = t & 63;
  const int pair = w >> 2, nt = w & 3;
  const int t1 = pair*2, t2 = t1 + 1;
  const int tile0 = blockIdx.x * tpb;

  // producer mapping (x -> fragment transpose)
  const int pp = t & 15;                     // position within tile
  const int ip = t >> 4;                     // i-pair (i = 2*ip, 2*ip+1)
  const int d32 = (ip >> 4)*256 + (16*((ip >> 2) & 3) + pp)*4 + (ip & 3);

  float4 X[8];                               // prefetched x rows (32 VGPR)

  auto loadX = [&](int tile) {
    const float4* s4 = (const float4*)(x + ((size_t)(tile*16 + pp))*1024 + ip*32);
    #pragma unroll
    for (int k = 0; k < 8; ++k) X[k] = s4[k];
  };
  auto convert = [&]() {                     // X regs -> F fragments
    u32* lw = (u32*)F;
    const float* v = (const float*)X;
    #pragma unroll
    for (int y = 0; y < 16; ++y)
      lw[y*512 + d32] = (u32)f2bf(v[y]) | ((u32)f2bf(v[16 + y]) << 16);
  };

  loadX(tile0);
  convert();
  if (tpb > 1) loadX(tile0 + 1);
  BARRIER();                                 // F(tile0) published

  for (int s = 0; s < tpb; ++s) {
    // ---- MFMA phase: grade-grouped so each wb fragment loads once ----
    f32x4 acc1[16], acc2[16];
    #pragma unroll
    for (int y = 0; y < 16; ++y) {
      acc1[y] = (f32x4){0.f,0.f,0.f,0.f};
      acc2[y] = (f32x4){0.f,0.f,0.f,0.f};
    }

    #pragma unroll
    for (int g = 0; g < 5; ++g) {
      bf16x8 bg1[2], bg2[2], be1[2], be2[2];
      #pragma unroll
      for (int kt = 0; kt < 2; ++kt) {
        bg1[kt] = *(const bf16x8*)(wb + ((size_t)((t1*9 + g)*8 + nt*2 + kt))*512 + l*8);
        bg2[kt] = *(const bf16x8*)(wb + ((size_t)((t2*9 + g)*8 + nt*2 + kt))*512 + l*8);
      }
      if (g >= 1) {
        #pragma unroll
        for (int kt = 0; kt < 2; ++kt) {
          be1[kt] = *(const bf16x8*)(wb + ((size_t)((t1*9 + 4+g)*8 + nt*2 + kt))*512 + l*8);
          be2[kt] = *(const bf16x8*)(wb + ((size_t)((t2*9 + 4+g)*8 + nt*2 + kt))*512 + l*8);
        }
      }
      #pragma unroll
      for (int yi = 0; yi < GRADE_N[g]; ++yi) {
        const int y = GRADE_Y[g][yi];
        #pragma unroll
        for (int kt = 0; kt < 2; ++kt) {
          bf16x8 a = *(const bf16x8*)&F[y*1024 + kt*512 + l*8];
          acc1[y] = __builtin_amdgcn_mfma_f32_16x16x32_bf16(a, bg1[kt], acc1[y], 0, 0, 0);
          acc2[y] = __builtin_amdgcn_mfma_f32_16x16x32_bf16(a, bg2[kt], acc2[y], 0, 0, 0);
        }
        if (y & 1) {                         // left-e0 map, source plane y^1
          #pragma unroll
          for (int kt = 0; kt < 2; ++kt) {
            bf16x8 a = *(const bf16x8*)&F[(y^1)*1024 + kt*512 + l*8];
            acc1[y] = __builtin_amdgcn_mfma_f32_16x16x32_bf16(a, be1[kt], acc1[y], 0, 0, 0);
            acc2[y] = __builtin_amdgcn_mfma_f32_16x16x32_bf16(a, be2[kt], acc2[y], 0, 0, 0);
          }
        }
      }
    }

    BARRIER();                               // all waves done reading F

    // ---- epilogue: bilinear + wave-local LDS transpose + 1KB stores ----
    const int tile = tile0 + s;
    f32x4* scr = (f32x4*)F;                  // reuse F: 8 waves x 4KB
    const int pg = l >> 4, c16 = l & 15;

    #pragma unroll
    for (int r = 0; r < 4; ++r) {
      float g1[16], g2[16];
      #pragma unroll
      for (int y = 0; y < 16; ++y) { g1[y] = acc1[y][r]; g2[y] = acc2[y][r]; }
      float o[16];
      #pragma unroll
      for (int k = 0; k < 16; ++k) o[k] = 0.0f;

      if (pair == 0) {
        #pragma unroll
        for (int a = 0; a < 16; ++a)
          #pragma unroll
          for (int b = 0; b < 16; ++b) {
            const float sg = TBL.gp[a][b];
            if (sg != 0.0f) o[a ^ b] += sg * g1[a] * g2[b];
          }
        #pragma unroll
        for (int k = 0; k < 16; ++k) o[k] *= 1e-5f;
      } else {
        const float r15 = ref[(size_t)(tile*16 + pg*4 + r)*16 + 15];
        #pragma unroll
        for (int a = 0; a < 16; ++a)
          #pragma unroll
          for (int b = 0; b < 16; ++b) {
            const float sg = TBL.jn[a][b];
            if (sg != 0.0f) o[a & b] += sg * g1[a] * g2[b];
          }
        #pragma unroll
        for (int k = 0; k < 16; ++k) o[k] *= r15;
      }

      #pragma unroll
      for (int j = 0; j < 4; ++j) {
        const int loc = pg*64 + c16*4 + j;
        const int f4s = loc ^ ((loc >> 3) & 7);
        scr[w*256 + f4s] = (f32x4){o[j*4], o[j*4+1], o[j*4+2], o[j*4+3]};
      }
      #pragma unroll
      for (int q = 0; q < 4; ++q) {
        const int loc = q*64 + l;
        const int f4s = loc ^ ((loc >> 3) & 7);
        const f32x4 v = scr[w*256 + f4s];
        float4* dst = (float4*)(out + ((size_t)(tile*16 + q*4 + r)*128 + pair*64 + nt*16)*16) + l;
        *dst = make_float4(v[0], v[1], v[2], v[3]);
      }
    }

    if (s + 1 < tpb) {
      BARRIER();                             // scratch reads done block-wide
      convert();                             // X(s+1) -> F (vmcnt auto on X use)
      if (s + 2 < tpb) loadX(tile0 + s + 2); // refill X; in flight across next phases
      BARRIER();                             // F(s+1) published
    }
  }
}

// =====================================================================
// Fallback: exact-fp32 scalar kernel (used if ws too small / odd shape)
// =====================================================================
#define P_TILE 8
#define I_CHUNK 4

__global__ __launch_bounds__(256) void gbl_fused(
    const float* __restrict__ x, const float* __restrict__ ref,
    const float* __restrict__ wg1, const float* __restrict__ wg2,
    const float* __restrict__ wj1, const float* __restrict__ wj2,
    float* __restrict__ out)
{
  __shared__ float lds_x[P_TILE * 1024];
  __shared__ float lds_w[2 * I_CHUNK * 576];

  const int t    = threadIdx.x;
  const int tile = blockIdx.x >> 1;
  const int tau  = blockIdx.x & 1;
  const float* __restrict__ w1g = tau ? wj1 : wg1;
  const float* __restrict__ w2g = tau ? wj2 : wg2;

  const int c  = t & 63;
  const int ps = t >> 6;

  {
    const float4* __restrict__ gx = (const float4*)(x + (size_t)tile * (P_TILE * 1024));
    float4* lx = (float4*)lds_x;
    #pragma unroll
    for (int k = 0; k < 8; ++k) lx[t + k * 256] = gx[t + k * 256];
  }

  float acc1[2][16], acc2[2][16];
  #pragma unroll
  for (int s = 0; s < 2; ++s)
    #pragma unroll
    for (int y = 0; y < 16; ++y) { acc1[s][y] = 0.0f; acc2[s][y] = 0.0f; }

  for (int i0 = 0; i0 < 64; i0 += I_CHUNK) {
    __syncthreads();
    #pragma unroll
    for (int k = 0; k < 9; ++k) {
      const int e  = t + k * 256;
      const int cc = e / 36;
      const int r  = e % 36;
      const int il = r / 9;
      const int b  = r % 9;
      lds_w[ il            * 576 + cc * 9 + b] = w1g[cc * 576 + i0 * 9 + r];
      lds_w[(I_CHUNK + il) * 576 + cc * 9 + b] = w2g[cc * 576 + i0 * 9 + r];
    }
    __syncthreads();

    #pragma unroll
    for (int il = 0; il < I_CHUNK; ++il) {
      float w1[9], w2[9];
      #pragma unroll
      for (int b = 0; b < 9; ++b) {
        w1[b] = lds_w[ il            * 576 + c * 9 + b];
        w2[b] = lds_w[(I_CHUNK + il) * 576 + c * 9 + b];
      }
      #pragma unroll
      for (int s = 0; s < 2; ++s) {
        const int p = ps + s * 4;
        const float4* xr = (const float4*)&lds_x[p * 1024 + (i0 + il) * 16];
        const float4 xa = xr[0], xb = xr[1], xc4 = xr[2], xd = xr[3];
        const float xv[16] = { xa.x, xa.y, xa.z, xa.w, xb.x, xb.y, xb.z, xb.w,
                               xc4.x, xc4.y, xc4.z, xc4.w, xd.x, xd.y, xd.z, xd.w };
        #pragma unroll
        for (int y = 0; y < 16; ++y) {
          acc1[s][y] += w1[PC[y]] * xv[y];
          acc2[s][y] += w2[PC[y]] * xv[y];
        }
        #pragma unroll
        for (int y = 1; y < 16; y += 2) {
          acc1[s][y] += w1[4 + PC[y]] * xv[y ^ 1];
          acc2[s][y] += w2[4 + PC[y]] * xv[y ^ 1];
        }
      }
    }
  }

  #pragma unroll
  for (int s = 0; s < 2; ++s) {
    const int p = ps + s * 4;
    const size_t pos = (size_t)tile * P_TILE + p;
    float o[16];
    #pragma unroll
    for (int k = 0; k < 16; ++k) o[k] = 0.0f;

    if (tau == 0) {
      #pragma unroll
      for (int a = 0; a < 16; ++a)
        #pragma unroll
        for (int b = 0; b < 16; ++b) {
          const float sg = TBL.gp[a][b];
          if (sg != 0.0f) o[a ^ b] += sg * acc1[s][a] * acc2[s][b];
        }
      #pragma unroll
      for (int k = 0; k < 16; ++k) o[k] *= 1e-5f;
    } else {
      const float r15 = ref[pos * 16 + 15];
      #pragma unroll
      for (int a = 0; a < 16; ++a)
        #pragma unroll
        for (int b = 0; b < 16; ++b) {
          const float sg = TBL.jn[a][b];
          if (sg != 0.0f) o[a & b] += sg * acc1[s][a] * acc2[s][b];
        }
      #pragma unroll
      for (int k = 0; k < 16; ++k) o[k] *= r15;
    }

    float4* po = (float4*)(out + (pos * 128 + (size_t)tau * 64 + c) * 16);
    po[0] = make_float4(o[0],  o[1],  o[2],  o[3]);
    po[1] = make_float4(o[4],  o[5],  o[6],  o[7]);
    po[2] = make_float4(o[8],  o[9],  o[10], o[11]);
    po[3] = make_float4(o[12], o[13], o[14], o[15]);
  }
}

// =====================================================================
extern "C" void kernel_launch(void* const* d_in, const int* in_sizes, int n_in,
                              void* d_out, int out_size, void* d_ws, size_t ws_size,
                              hipStream_t stream) {
  const float* x   = (const float*)d_in[0];
  const float* ref = (const float*)d_in[1];
  const float* wg1 = (const float*)d_in[2];
  const float* wg2 = (const float*)d_in[3];
  const float* wj1 = (const float*)d_in[4];
  const float* wj2 = (const float*)d_in[5];
  float* outp = (float*)d_out;

  const int npos = in_sizes[0] / (64 * 16);     // B*N

  if (ws_size >= 294912 && (npos % 16) == 0) {
    const int tiles = npos / 16;
    int grid, tpb;
    if      (tiles % 256 == 0) { grid = 256;   tpb = tiles / 256; }
    else                       { grid = tiles; tpb = 1; }
    u16* wb = (u16*)d_ws;
    k_wb  <<<576, 256, 0, stream>>>(wg1, wg2, wj1, wj2, wb);
    k_pipe<<<grid, 512, 0, stream>>>(x, wb, ref, outp, tpb);
  } else {
    const int grid = (npos / P_TILE) * 2;
    gbl_fused<<<grid, 256, 0, stream>>>(x, ref, wg1, wg2, wj1, wj2, outp);
  }
}

// Round 7
// 131.278 us; speedup vs baseline: 1.0302x; 1.0302x over previous
//
#include <hip/hip_runtime.h>

typedef unsigned short u16;
typedef unsigned int   u32;
typedef __attribute__((ext_vector_type(4))) float f32x4;
typedef __attribute__((ext_vector_type(8))) short bf16x8;

// ---------- compile-time Cl(3,0,1) tables ----------
constexpr int pcf(int x){ int c=0; while(x){ c += x&1; x>>=1; } return c; }
constexpr int signexp(int a,int b){ int s=0; a>>=1; while(a){ s += pcf(a&b); a>>=1; } return s&1; }
constexpr float sgnf(int a,int b){ return signexp(a,b) ? -1.0f : 1.0f; }
constexpr float sDf(int a){ return sgnf(a, a^15); }

struct Tbl {
  float gp[16][16];   // g1[a]*g2[b] -> out[a^b], 0 if e0 overlap
  float jn[16][16];   // j1[a]*j2[b] -> out[a&b], 0 unless a|b==15
};
constexpr Tbl make_tbl(){
  Tbl t{};
  for(int a=0;a<16;a++){
    for(int b=0;b<16;b++){
      t.gp[a][b] = (a & b & 1) ? 0.0f : sgnf(a,b);
      t.jn[a][b] = ((a|b)==15) ? sDf(a)*sDf(b)*sDf(a&b)*sgnf(a^15,b^15) : 0.0f;
    }
  }
  return t;
}
constexpr Tbl TBL = make_tbl();
constexpr int PC[16] = {0,1,1,2,1,2,2,3,1,2,2,3,2,3,3,4};

// y-planes grouped by grade (pc). Verified weight-index formula:
// out[y] += w[pc(y)]*x[y]  and for odd y: out[y] += w[4+pc(y)]*x[y^1]
constexpr int GRADE_Y[5][6] = {{0,0,0,0,0,0},{1,2,4,8,0,0},{3,5,6,9,10,12},{7,11,13,14,0,0},{15,0,0,0,0,0}};
constexpr int GRADE_N[5] = {1,4,6,4,1};

__device__ __forceinline__ u16 f2bf(float f){
  union { float f; unsigned u; } v; v.f = f;
  unsigned r = v.u + 0x7fffu + ((v.u >> 16) & 1u);   // RNE
  return (u16)(r >> 16);
}

// raw barrier: per-wave LDS drain + s_barrier, NO vmcnt drain (prefetch
// loads stay in flight across it). "memory" clobber stops LDS caching/CSE.
#define BARRIER() do {                                          \
  asm volatile("s_waitcnt lgkmcnt(0)" ::: "memory");            \
  __builtin_amdgcn_sched_barrier(0);                            \
  __builtin_amdgcn_s_barrier();                                 \
  __builtin_amdgcn_sched_barrier(0);                            \
} while (0)

// =====================================================================
// Kernel: weights fp32 -> bf16 B-fragments
// wb offset: ((t*9+b)*8 + nt*2 + kt)*512 + lane*8 + j
//   nt = c>>4, lane = 16*((i>>3)&3) + (c&15), kt = i>>5, j = i&7
// =====================================================================
__global__ __launch_bounds__(256) void k_wb(const float* __restrict__ wg1,
                                            const float* __restrict__ wg2,
                                            const float* __restrict__ wj1,
                                            const float* __restrict__ wj2,
                                            u16* __restrict__ wb)
{
  const int e = blockIdx.x*256 + threadIdx.x;      // 0 .. 147455
  const int t   = e / 36864;                        // tensor (wave-uniform)
  const int rem = e % 36864;                        // c*576 + i*9 + b
  const int c = rem / 576, r2 = rem % 576, i = r2 / 9, b = r2 % 9;
  const float* wp = (t < 2) ? (t ? wg2 : wg1) : ((t == 2) ? wj1 : wj2);
  const float v = wp[rem];
  const int dst = ((t*9 + b)*8 + (c>>4)*2 + (i>>5))*512
                + (16*((i>>3)&3) + (c&15))*8 + (i&7);
  wb[dst] = f2bf(v);
}

// =====================================================================
// Persistent pipelined kernel: tpb tiles per block, register prefetch,
// raw barriers (3/iter) keep next-tile loads in flight across phases.
// 512 thr = 8 waves: pair = w>>2 (0:gp 1:jn), nt = w&3.
//
// __launch_bounds__(512, 1): hipcc empirically treats the 2nd arg as
// CUDA-style min-BLOCKS-per-CU ((512,2) -> 16 waves/CU -> 128-reg cap,
// observed VGPR_Count=128 + spill in rounds 5/6). (512,1) -> 8 waves/CU
// -> 2 waves/SIMD -> 256-reg budget under either semantics.
// =====================================================================
__global__ __launch_bounds__(512, 1)
void k_pipe(const float* __restrict__ x, const u16* __restrict__ wb,
            const float* __restrict__ ref, float* __restrict__ out,
            int tpb)
{
  __shared__ __align__(16) u16 F[16384];     // 32 KB frag buffer / scratch

  const int t = threadIdx.x, w = t >> 6, l = t & 63;
  const int pair = w >> 2, nt = w & 3;
  const int t1 = pair*2, t2 = t1 + 1;
  const int tile0 = blockIdx.x * tpb;

  // producer mapping (x -> fragment transpose)
  const int pp = t & 15;                     // position within tile
  const int ip = t >> 4;                     // i-pair (i = 2*ip, 2*ip+1)
  const int d32 = (ip >> 4)*256 + (16*((ip >> 2) & 3) + pp)*4 + (ip & 3);

  float4 X[8];                               // prefetched x rows (32 VGPR)

  auto loadX = [&](int tile) {
    const float4* s4 = (const float4*)(x + ((size_t)(tile*16 + pp))*1024 + ip*32);
    #pragma unroll
    for (int k = 0; k < 8; ++k) X[k] = s4[k];
  };
  auto convert = [&]() {                     // X regs -> F fragments
    u32* lw = (u32*)F;
    const float* v = (const float*)X;
    #pragma unroll
    for (int y = 0; y < 16; ++y)
      lw[y*512 + d32] = (u32)f2bf(v[y]) | ((u32)f2bf(v[16 + y]) << 16);
  };

  loadX(tile0);
  convert();
  if (tpb > 1) loadX(tile0 + 1);
  BARRIER();                                 // F(tile0) published

  for (int s = 0; s < tpb; ++s) {
    // ---- MFMA phase: grade-grouped so each wb fragment loads once ----
    f32x4 acc1[16], acc2[16];
    #pragma unroll
    for (int y = 0; y < 16; ++y) {
      acc1[y] = (f32x4){0.f,0.f,0.f,0.f};
      acc2[y] = (f32x4){0.f,0.f,0.f,0.f};
    }

    #pragma unroll
    for (int g = 0; g < 5; ++g) {
      bf16x8 bg1[2], bg2[2], be1[2], be2[2];
      #pragma unroll
      for (int kt = 0; kt < 2; ++kt) {
        bg1[kt] = *(const bf16x8*)(wb + ((size_t)((t1*9 + g)*8 + nt*2 + kt))*512 + l*8);
        bg2[kt] = *(const bf16x8*)(wb + ((size_t)((t2*9 + g)*8 + nt*2 + kt))*512 + l*8);
      }
      if (g >= 1) {
        #pragma unroll
        for (int kt = 0; kt < 2; ++kt) {
          be1[kt] = *(const bf16x8*)(wb + ((size_t)((t1*9 + 4+g)*8 + nt*2 + kt))*512 + l*8);
          be2[kt] = *(const bf16x8*)(wb + ((size_t)((t2*9 + 4+g)*8 + nt*2 + kt))*512 + l*8);
        }
      }
      #pragma unroll
      for (int yi = 0; yi < GRADE_N[g]; ++yi) {
        const int y = GRADE_Y[g][yi];
        #pragma unroll
        for (int kt = 0; kt < 2; ++kt) {
          bf16x8 a = *(const bf16x8*)&F[y*1024 + kt*512 + l*8];
          acc1[y] = __builtin_amdgcn_mfma_f32_16x16x32_bf16(a, bg1[kt], acc1[y], 0, 0, 0);
          acc2[y] = __builtin_amdgcn_mfma_f32_16x16x32_bf16(a, bg2[kt], acc2[y], 0, 0, 0);
        }
        if (y & 1) {                         // left-e0 map, source plane y^1
          #pragma unroll
          for (int kt = 0; kt < 2; ++kt) {
            bf16x8 a = *(const bf16x8*)&F[(y^1)*1024 + kt*512 + l*8];
            acc1[y] = __builtin_amdgcn_mfma_f32_16x16x32_bf16(a, be1[kt], acc1[y], 0, 0, 0);
            acc2[y] = __builtin_amdgcn_mfma_f32_16x16x32_bf16(a, be2[kt], acc2[y], 0, 0, 0);
          }
        }
      }
    }

    BARRIER();                               // all waves done reading F

    // ---- epilogue: bilinear + wave-local LDS transpose + 1KB stores ----
    const int tile = tile0 + s;
    f32x4* scr = (f32x4*)F;                  // reuse F: 8 waves x 4KB
    const int pg = l >> 4, c16 = l & 15;

    #pragma unroll
    for (int r = 0; r < 4; ++r) {
      float g1[16], g2[16];
      #pragma unroll
      for (int y = 0; y < 16; ++y) { g1[y] = acc1[y][r]; g2[y] = acc2[y][r]; }
      float o[16];
      #pragma unroll
      for (int k = 0; k < 16; ++k) o[k] = 0.0f;

      if (pair == 0) {
        #pragma unroll
        for (int a = 0; a < 16; ++a)
          #pragma unroll
          for (int b = 0; b < 16; ++b) {
            const float sg = TBL.gp[a][b];
            if (sg != 0.0f) o[a ^ b] += sg * g1[a] * g2[b];
          }
        #pragma unroll
        for (int k = 0; k < 16; ++k) o[k] *= 1e-5f;
      } else {
        const float r15 = ref[(size_t)(tile*16 + pg*4 + r)*16 + 15];
        #pragma unroll
        for (int a = 0; a < 16; ++a)
          #pragma unroll
          for (int b = 0; b < 16; ++b) {
            const float sg = TBL.jn[a][b];
            if (sg != 0.0f) o[a & b] += sg * g1[a] * g2[b];
          }
        #pragma unroll
        for (int k = 0; k < 16; ++k) o[k] *= r15;
      }

      #pragma unroll
      for (int j = 0; j < 4; ++j) {
        const int loc = pg*64 + c16*4 + j;
        const int f4s = loc ^ ((loc >> 3) & 7);
        scr[w*256 + f4s] = (f32x4){o[j*4], o[j*4+1], o[j*4+2], o[j*4+3]};
      }
      #pragma unroll
      for (int q = 0; q < 4; ++q) {
        const int loc = q*64 + l;
        const int f4s = loc ^ ((loc >> 3) & 7);
        const f32x4 v = scr[w*256 + f4s];
        float4* dst = (float4*)(out + ((size_t)(tile*16 + q*4 + r)*128 + pair*64 + nt*16)*16) + l;
        *dst = make_float4(v[0], v[1], v[2], v[3]);
      }
    }

    if (s + 1 < tpb) {
      BARRIER();                             // scratch reads done block-wide
      convert();                             // X(s+1) -> F (vmcnt auto on X use)
      if (s + 2 < tpb) loadX(tile0 + s + 2); // refill X; in flight across next phases
      BARRIER();                             // F(s+1) published
    }
  }
}

// =====================================================================
// Fallback: exact-fp32 scalar kernel (used if ws too small / odd shape)
// =====================================================================
#define P_TILE 8
#define I_CHUNK 4

__global__ __launch_bounds__(256) void gbl_fused(
    const float* __restrict__ x, const float* __restrict__ ref,
    const float* __restrict__ wg1, const float* __restrict__ wg2,
    const float* __restrict__ wj1, const float* __restrict__ wj2,
    float* __restrict__ out)
{
  __shared__ float lds_x[P_TILE * 1024];
  __shared__ float lds_w[2 * I_CHUNK * 576];

  const int t    = threadIdx.x;
  const int tile = blockIdx.x >> 1;
  const int tau  = blockIdx.x & 1;
  const float* __restrict__ w1g = tau ? wj1 : wg1;
  const float* __restrict__ w2g = tau ? wj2 : wg2;

  const int c  = t & 63;
  const int ps = t >> 6;

  {
    const float4* __restrict__ gx = (const float4*)(x + (size_t)tile * (P_TILE * 1024));
    float4* lx = (float4*)lds_x;
    #pragma unroll
    for (int k = 0; k < 8; ++k) lx[t + k * 256] = gx[t + k * 256];
  }

  float acc1[2][16], acc2[2][16];
  #pragma unroll
  for (int s = 0; s < 2; ++s)
    #pragma unroll
    for (int y = 0; y < 16; ++y) { acc1[s][y] = 0.0f; acc2[s][y] = 0.0f; }

  for (int i0 = 0; i0 < 64; i0 += I_CHUNK) {
    __syncthreads();
    #pragma unroll
    for (int k = 0; k < 9; ++k) {
      const int e  = t + k * 256;
      const int cc = e / 36;
      const int r  = e % 36;
      const int il = r / 9;
      const int b  = r % 9;
      lds_w[ il            * 576 + cc * 9 + b] = w1g[cc * 576 + i0 * 9 + r];
      lds_w[(I_CHUNK + il) * 576 + cc * 9 + b] = w2g[cc * 576 + i0 * 9 + r];
    }
    __syncthreads();

    #pragma unroll
    for (int il = 0; il < I_CHUNK; ++il) {
      float w1[9], w2[9];
      #pragma unroll
      for (int b = 0; b < 9; ++b) {
        w1[b] = lds_w[ il            * 576 + c * 9 + b];
        w2[b] = lds_w[(I_CHUNK + il) * 576 + c * 9 + b];
      }
      #pragma unroll
      for (int s = 0; s < 2; ++s) {
        const int p = ps + s * 4;
        const float4* xr = (const float4*)&lds_x[p * 1024 + (i0 + il) * 16];
        const float4 xa = xr[0], xb = xr[1], xc4 = xr[2], xd = xr[3];
        const float xv[16] = { xa.x, xa.y, xa.z, xa.w, xb.x, xb.y, xb.z, xb.w,
                               xc4.x, xc4.y, xc4.z, xc4.w, xd.x, xd.y, xd.z, xd.w };
        #pragma unroll
        for (int y = 0; y < 16; ++y) {
          acc1[s][y] += w1[PC[y]] * xv[y];
          acc2[s][y] += w2[PC[y]] * xv[y];
        }
        #pragma unroll
        for (int y = 1; y < 16; y += 2) {
          acc1[s][y] += w1[4 + PC[y]] * xv[y ^ 1];
          acc2[s][y] += w2[4 + PC[y]] * xv[y ^ 1];
        }
      }
    }
  }

  #pragma unroll
  for (int s = 0; s < 2; ++s) {
    const int p = ps + s * 4;
    const size_t pos = (size_t)tile * P_TILE + p;
    float o[16];
    #pragma unroll
    for (int k = 0; k < 16; ++k) o[k] = 0.0f;

    if (tau == 0) {
      #pragma unroll
      for (int a = 0; a < 16; ++a)
        #pragma unroll
        for (int b = 0; b < 16; ++b) {
          const float sg = TBL.gp[a][b];
          if (sg != 0.0f) o[a ^ b] += sg * acc1[s][a] * acc2[s][b];
        }
      #pragma unroll
      for (int k = 0; k < 16; ++k) o[k] *= 1e-5f;
    } else {
      const float r15 = ref[pos * 16 + 15];
      #pragma unroll
      for (int a = 0; a < 16; ++a)
        #pragma unroll
        for (int b = 0; b < 16; ++b) {
          const float sg = TBL.jn[a][b];
          if (sg != 0.0f) o[a & b] += sg * acc1[s][a] * acc2[s][b];
        }
      #pragma unroll
      for (int k = 0; k < 16; ++k) o[k] *= r15;
    }

    float4* po = (float4*)(out + (pos * 128 + (size_t)tau * 64 + c) * 16);
    po[0] = make_float4(o[0],  o[1],  o[2],  o[3]);
    po[1] = make_float4(o[4],  o[5],  o[6],  o[7]);
    po[2] = make_float4(o[8],  o[9],  o[10], o[11]);
    po[3] = make_float4(o[12], o[13], o[14], o[15]);
  }
}

// =====================================================================
extern "C" void kernel_launch(void* const* d_in, const int* in_sizes, int n_in,
                              void* d_out, int out_size, void* d_ws, size_t ws_size,
                              hipStream_t stream) {
  const float* x   = (const float*)d_in[0];
  const float* ref = (const float*)d_in[1];
  const float* wg1 = (const float*)d_in[2];
  const float* wg2 = (const float*)d_in[3];
  const float* wj1 = (const float*)d_in[4];
  const float* wj2 = (const float*)d_in[5];
  float* outp = (float*)d_out;

  const int npos = in_sizes[0] / (64 * 16);     // B*N

  if (ws_size >= 294912 && (npos % 16) == 0) {
    const int tiles = npos / 16;
    int grid, tpb;
    if      (tiles % 256 == 0) { grid = 256;   tpb = tiles / 256; }
    else                       { grid = tiles; tpb = 1; }
    u16* wb = (u16*)d_ws;
    k_wb  <<<576, 256, 0, stream>>>(wg1, wg2, wj1, wj2, wb);
    k_pipe<<<grid, 512, 0, stream>>>(x, wb, ref, outp, tpb);
  } else {
    const int grid = (npos / P_TILE) * 2;
    gbl_fused<<<grid, 256, 0, stream>>>(x, ref, wg1, wg2, wj1, wj2, outp);
  }
}

// Round 8
// 97.233 us; speedup vs baseline: 1.3909x; 1.3501x over previous
//
#include <hip/hip_runtime.h>

typedef unsigned short u16;
typedef unsigned int   u32;
typedef __attribute__((ext_vector_type(4))) float f32x4;
typedef __attribute__((ext_vector_type(8))) short bf16x8;

// ---------- compile-time Cl(3,0,1) tables ----------
constexpr int pcf(int x){ int c=0; while(x){ c += x&1; x>>=1; } return c; }
constexpr int signexp(int a,int b){ int s=0; a>>=1; while(a){ s += pcf(a&b); a>>=1; } return s&1; }
constexpr float sgnf(int a,int b){ return signexp(a,b) ? -1.0f : 1.0f; }
constexpr float sDf(int a){ return sgnf(a, a^15); }

struct Tbl {
  float gp[16][16];   // g1[a]*g2[b] -> out[a^b], 0 if e0 overlap
  float jn[16][16];   // j1[a]*j2[b] -> out[a&b], 0 unless a|b==15
};
constexpr Tbl make_tbl(){
  Tbl t{};
  for(int a=0;a<16;a++){
    for(int b=0;b<16;b++){
      t.gp[a][b] = (a & b & 1) ? 0.0f : sgnf(a,b);
      t.jn[a][b] = ((a|b)==15) ? sDf(a)*sDf(b)*sDf(a&b)*sgnf(a^15,b^15) : 0.0f;
    }
  }
  return t;
}
constexpr Tbl TBL = make_tbl();
constexpr int PC[16] = {0,1,1,2,1,2,2,3,1,2,2,3,2,3,3,4};

// y-planes grouped by grade (pc). Verified weight-index formula:
// out[y] += w[pc(y)]*x[y]  and for odd y: out[y] += w[4+pc(y)]*x[y^1]
constexpr int GRADE_Y[5][6] = {{0,0,0,0,0,0},{1,2,4,8,0,0},{3,5,6,9,10,12},{7,11,13,14,0,0},{15,0,0,0,0,0}};
constexpr int GRADE_N[5] = {1,4,6,4,1};

__device__ __forceinline__ u16 f2bf(float f){
  union { float f; unsigned u; } v; v.f = f;
  unsigned r = v.u + 0x7fffu + ((v.u >> 16) & 1u);   // RNE
  return (u16)(r >> 16);
}

// =====================================================================
// Kernel: weights fp32 -> bf16 B-fragments
// wb offset: ((t*9+b)*8 + nt*2 + kt)*512 + lane*8 + j
//   nt = c>>4, lane = 16*((i>>3)&3) + (c&15), kt = i>>5, j = i&7
// =====================================================================
__global__ __launch_bounds__(256) void k_wb(const float* __restrict__ wg1,
                                            const float* __restrict__ wg2,
                                            const float* __restrict__ wj1,
                                            const float* __restrict__ wj2,
                                            u16* __restrict__ wb)
{
  const int e = blockIdx.x*256 + threadIdx.x;      // 0 .. 147455
  const int t   = e / 36864;                        // tensor (wave-uniform)
  const int rem = e % 36864;                        // c*576 + i*9 + b
  const int c = rem / 576, r2 = rem % 576, i = r2 / 9, b = r2 % 9;
  const float* wp = (t < 2) ? (t ? wg2 : wg1) : ((t == 2) ? wj1 : wj2);
  const float v = wp[rem];
  const int dst = ((t*9 + b)*8 + (c>>4)*2 + (i>>5))*512
                + (16*((i>>3)&3) + (c&15))*8 + (i&7);
  wb[dst] = f2bf(v);
}

// =====================================================================
// Half-tile kernel: ONE output pair (gp or jn) of one 16-pos tile per
// 256-thread block (4 waves, wave = 16-channel slice nt).
//
// Register model (gfx950 unified file, empirical rounds 4-7):
//   acc -> 128 AGPR; arch-VGPR cap 128; NO state held across phases
//   -> no scratch spill. 4 waves x 256 total regs + 32 KB LDS
//   -> 2 blocks/CU co-resident with INDEPENDENT barrier domains:
//   block-level overlap of load/MFMA/epilogue/store replaces the
//   register prefetch that spilled in rounds 5-7.
// pair = blockIdx.x & 1 (fastest-varying: gp/jn of same tile adjacent
// in dispatch -> x hits L2/L3 on the second read).
// =====================================================================
__global__ __launch_bounds__(256)
void k_half(const float* __restrict__ x, const u16* __restrict__ wb,
            const float* __restrict__ ref, float* __restrict__ out)
{
  __shared__ __align__(16) u16 F[16384];     // 32 KB frag buffer / scratch

  const int t = threadIdx.x, w = t >> 6, l = t & 63;
  const int pair = blockIdx.x & 1;
  const int tile = blockIdx.x >> 1;
  const int nt = w;                          // 16-channel slice
  const int t1 = pair*2, t2 = t1 + 1;        // tensor indices

  // ---- phase 1: x -> bf16 fragment transpose (each thread: 2 i-pairs)
  {
    const int pp  = t & 15;                  // position within tile
    const int ip0 = t >> 4;                  // 0..15
    #pragma unroll
    for (int h = 0; h < 2; ++h) {
      const int ip = ip0 + h*16;             // i-pair (i = 2*ip, 2*ip+1)
      float4 X[8];
      const float4* s4 = (const float4*)(x + ((size_t)(tile*16 + pp))*1024 + ip*32);
      #pragma unroll
      for (int k = 0; k < 8; ++k) X[k] = s4[k];
      const int d32 = h*256 + (16*((ip0 >> 2) & 3) + pp)*4 + (ip0 & 3);
      u32* lw = (u32*)F;
      const float* v = (const float*)X;
      #pragma unroll
      for (int y = 0; y < 16; ++y)
        lw[y*512 + d32] = (u32)f2bf(v[y]) | ((u32)f2bf(v[16 + y]) << 16);
    }
  }

  __syncthreads();                           // fragments published

  // ---- phase 2: MFMA linears (grade-grouped wb loads) ----
  f32x4 acc1[16], acc2[16];
  #pragma unroll
  for (int y = 0; y < 16; ++y) {
    acc1[y] = (f32x4){0.f,0.f,0.f,0.f};
    acc2[y] = (f32x4){0.f,0.f,0.f,0.f};
  }

  #pragma unroll
  for (int g = 0; g < 5; ++g) {
    bf16x8 bg1[2], bg2[2], be1[2], be2[2];
    #pragma unroll
    for (int kt = 0; kt < 2; ++kt) {
      bg1[kt] = *(const bf16x8*)(wb + ((size_t)((t1*9 + g)*8 + nt*2 + kt))*512 + l*8);
      bg2[kt] = *(const bf16x8*)(wb + ((size_t)((t2*9 + g)*8 + nt*2 + kt))*512 + l*8);
    }
    if (g >= 1) {
      #pragma unroll
      for (int kt = 0; kt < 2; ++kt) {
        be1[kt] = *(const bf16x8*)(wb + ((size_t)((t1*9 + 4+g)*8 + nt*2 + kt))*512 + l*8);
        be2[kt] = *(const bf16x8*)(wb + ((size_t)((t2*9 + 4+g)*8 + nt*2 + kt))*512 + l*8);
      }
    }
    #pragma unroll
    for (int yi = 0; yi < GRADE_N[g]; ++yi) {
      const int y = GRADE_Y[g][yi];
      #pragma unroll
      for (int kt = 0; kt < 2; ++kt) {
        bf16x8 a = *(const bf16x8*)&F[y*1024 + kt*512 + l*8];
        acc1[y] = __builtin_amdgcn_mfma_f32_16x16x32_bf16(a, bg1[kt], acc1[y], 0, 0, 0);
        acc2[y] = __builtin_amdgcn_mfma_f32_16x16x32_bf16(a, bg2[kt], acc2[y], 0, 0, 0);
      }
      if (y & 1) {                           // left-e0 map, source plane y^1
        #pragma unroll
        for (int kt = 0; kt < 2; ++kt) {
          bf16x8 a = *(const bf16x8*)&F[(y^1)*1024 + kt*512 + l*8];
          acc1[y] = __builtin_amdgcn_mfma_f32_16x16x32_bf16(a, be1[kt], acc1[y], 0, 0, 0);
          acc2[y] = __builtin_amdgcn_mfma_f32_16x16x32_bf16(a, be2[kt], acc2[y], 0, 0, 0);
        }
      }
    }
  }

  __syncthreads();                           // F reusable as scratch

  // ---- phase 3: bilinear + wave-local LDS transpose + 1KB stores ----
  f32x4* scr = (f32x4*)F;                    // 4 waves x 256 f32x4 (4 KB each)
  const int pg = l >> 4, c16 = l & 15;

  #pragma unroll
  for (int r = 0; r < 4; ++r) {
    float g1[16], g2[16];
    #pragma unroll
    for (int y = 0; y < 16; ++y) { g1[y] = acc1[y][r]; g2[y] = acc2[y][r]; }
    float o[16];
    #pragma unroll
    for (int k = 0; k < 16; ++k) o[k] = 0.0f;

    if (pair == 0) {
      #pragma unroll
      for (int a = 0; a < 16; ++a)
        #pragma unroll
        for (int b = 0; b < 16; ++b) {
          const float sg = TBL.gp[a][b];
          if (sg != 0.0f) o[a ^ b] += sg * g1[a] * g2[b];
        }
      #pragma unroll
      for (int k = 0; k < 16; ++k) o[k] *= 1e-5f;
    } else {
      const float r15 = ref[(size_t)(tile*16 + pg*4 + r)*16 + 15];
      #pragma unroll
      for (int a = 0; a < 16; ++a)
        #pragma unroll
        for (int b = 0; b < 16; ++b) {
          const float sg = TBL.jn[a][b];
          if (sg != 0.0f) o[a & b] += sg * g1[a] * g2[b];
        }
      #pragma unroll
      for (int k = 0; k < 16; ++k) o[k] *= r15;
    }

    #pragma unroll
    for (int j = 0; j < 4; ++j) {
      const int loc = pg*64 + c16*4 + j;
      const int f4s = loc ^ ((loc >> 3) & 7);
      scr[w*256 + f4s] = (f32x4){o[j*4], o[j*4+1], o[j*4+2], o[j*4+3]};
    }
    #pragma unroll
    for (int q = 0; q < 4; ++q) {
      const int loc = q*64 + l;
      const int f4s = loc ^ ((loc >> 3) & 7);
      const f32x4 v = scr[w*256 + f4s];
      float4* dst = (float4*)(out + ((size_t)(tile*16 + q*4 + r)*128 + pair*64 + nt*16)*16) + l;
      *dst = make_float4(v[0], v[1], v[2], v[3]);
    }
    __syncthreads();                         // scr slot reuse across r
  }
}

// =====================================================================
// Fallback: exact-fp32 scalar kernel (used if ws too small / odd shape)
// =====================================================================
#define P_TILE 8
#define I_CHUNK 4

__global__ __launch_bounds__(256) void gbl_fused(
    const float* __restrict__ x, const float* __restrict__ ref,
    const float* __restrict__ wg1, const float* __restrict__ wg2,
    const float* __restrict__ wj1, const float* __restrict__ wj2,
    float* __restrict__ out)
{
  __shared__ float lds_x[P_TILE * 1024];
  __shared__ float lds_w[2 * I_CHUNK * 576];

  const int t    = threadIdx.x;
  const int tile = blockIdx.x >> 1;
  const int tau  = blockIdx.x & 1;
  const float* __restrict__ w1g = tau ? wj1 : wg1;
  const float* __restrict__ w2g = tau ? wj2 : wg2;

  const int c  = t & 63;
  const int ps = t >> 6;

  {
    const float4* __restrict__ gx = (const float4*)(x + (size_t)tile * (P_TILE * 1024));
    float4* lx = (float4*)lds_x;
    #pragma unroll
    for (int k = 0; k < 8; ++k) lx[t + k * 256] = gx[t + k * 256];
  }

  float acc1[2][16], acc2[2][16];
  #pragma unroll
  for (int s = 0; s < 2; ++s)
    #pragma unroll
    for (int y = 0; y < 16; ++y) { acc1[s][y] = 0.0f; acc2[s][y] = 0.0f; }

  for (int i0 = 0; i0 < 64; i0 += I_CHUNK) {
    __syncthreads();
    #pragma unroll
    for (int k = 0; k < 9; ++k) {
      const int e  = t + k * 256;
      const int cc = e / 36;
      const int r  = e % 36;
      const int il = r / 9;
      const int b  = r % 9;
      lds_w[ il            * 576 + cc * 9 + b] = w1g[cc * 576 + i0 * 9 + r];
      lds_w[(I_CHUNK + il) * 576 + cc * 9 + b] = w2g[cc * 576 + i0 * 9 + r];
    }
    __syncthreads();

    #pragma unroll
    for (int il = 0; il < I_CHUNK; ++il) {
      float w1[9], w2[9];
      #pragma unroll
      for (int b = 0; b < 9; ++b) {
        w1[b] = lds_w[ il            * 576 + c * 9 + b];
        w2[b] = lds_w[(I_CHUNK + il) * 576 + c * 9 + b];
      }
      #pragma unroll
      for (int s = 0; s < 2; ++s) {
        const int p = ps + s * 4;
        const float4* xr = (const float4*)&lds_x[p * 1024 + (i0 + il) * 16];
        const float4 xa = xr[0], xb = xr[1], xc4 = xr[2], xd = xr[3];
        const float xv[16] = { xa.x, xa.y, xa.z, xa.w, xb.x, xb.y, xb.z, xb.w,
                               xc4.x, xc4.y, xc4.z, xc4.w, xd.x, xd.y, xd.z, xd.w };
        #pragma unroll
        for (int y = 0; y < 16; ++y) {
          acc1[s][y] += w1[PC[y]] * xv[y];
          acc2[s][y] += w2[PC[y]] * xv[y];
        }
        #pragma unroll
        for (int y = 1; y < 16; y += 2) {
          acc1[s][y] += w1[4 + PC[y]] * xv[y ^ 1];
          acc2[s][y] += w2[4 + PC[y]] * xv[y ^ 1];
        }
      }
    }
  }

  #pragma unroll
  for (int s = 0; s < 2; ++s) {
    const int p = ps + s * 4;
    const size_t pos = (size_t)tile * P_TILE + p;
    float o[16];
    #pragma unroll
    for (int k = 0; k < 16; ++k) o[k] = 0.0f;

    if (tau == 0) {
      #pragma unroll
      for (int a = 0; a < 16; ++a)
        #pragma unroll
        for (int b = 0; b < 16; ++b) {
          const float sg = TBL.gp[a][b];
          if (sg != 0.0f) o[a ^ b] += sg * acc1[s][a] * acc2[s][b];
        }
      #pragma unroll
      for (int k = 0; k < 16; ++k) o[k] *= 1e-5f;
    } else {
      const float r15 = ref[pos * 16 + 15];
      #pragma unroll
      for (int a = 0; a < 16; ++a)
        #pragma unroll
        for (int b = 0; b < 16; ++b) {
          const float sg = TBL.jn[a][b];
          if (sg != 0.0f) o[a & b] += sg * acc1[s][a] * acc2[s][b];
        }
      #pragma unroll
      for (int k = 0; k < 16; ++k) o[k] *= r15;
    }

    float4* po = (float4*)(out + (pos * 128 + (size_t)tau * 64 + c) * 16);
    po[0] = make_float4(o[0],  o[1],  o[2],  o[3]);
    po[1] = make_float4(o[4],  o[5],  o[6],  o[7]);
    po[2] = make_float4(o[8],  o[9],  o[10], o[11]);
    po[3] = make_float4(o[12], o[13], o[14], o[15]);
  }
}

// =====================================================================
extern "C" void kernel_launch(void* const* d_in, const int* in_sizes, int n_in,
                              void* d_out, int out_size, void* d_ws, size_t ws_size,
                              hipStream_t stream) {
  const float* x   = (const float*)d_in[0];
  const float* ref = (const float*)d_in[1];
  const float* wg1 = (const float*)d_in[2];
  const float* wg2 = (const float*)d_in[3];
  const float* wj1 = (const float*)d_in[4];
  const float* wj2 = (const float*)d_in[5];
  float* outp = (float*)d_out;

  const int npos = in_sizes[0] / (64 * 16);     // B*N

  if (ws_size >= 294912 && (npos % 16) == 0) {
    u16* wb = (u16*)d_ws;
    k_wb  <<<576, 256, 0, stream>>>(wg1, wg2, wj1, wj2, wb);
    k_half<<<(npos / 16) * 2, 256, 0, stream>>>(x, wb, ref, outp);
  } else {
    const int grid = (npos / P_TILE) * 2;
    gbl_fused<<<grid, 256, 0, stream>>>(x, ref, wg1, wg2, wj1, wj2, outp);
  }
}

// Round 9
// 89.351 us; speedup vs baseline: 1.5135x; 1.0882x over previous
//
#include <hip/hip_runtime.h>

typedef unsigned short u16;
typedef unsigned int   u32;
typedef __attribute__((ext_vector_type(4))) float f32x4;
typedef __attribute__((ext_vector_type(8))) short bf16x8;

// ---------- compile-time Cl(3,0,1) tables ----------
constexpr int pcf(int x){ int c=0; while(x){ c += x&1; x>>=1; } return c; }
constexpr int signexp(int a,int b){ int s=0; a>>=1; while(a){ s += pcf(a&b); a>>=1; } return s&1; }
constexpr float sgnf(int a,int b){ return signexp(a,b) ? -1.0f : 1.0f; }
constexpr float sDf(int a){ return sgnf(a, a^15); }

struct Tbl {
  float gp[16][16];   // g1[a]*g2[b] -> out[a^b], 0 if e0 overlap
  float jn[16][16];   // j1[a]*j2[b] -> out[a&b], 0 unless a|b==15
};
constexpr Tbl make_tbl(){
  Tbl t{};
  for(int a=0;a<16;a++){
    for(int b=0;b<16;b++){
      t.gp[a][b] = (a & b & 1) ? 0.0f : sgnf(a,b);
      t.jn[a][b] = ((a|b)==15) ? sDf(a)*sDf(b)*sDf(a&b)*sgnf(a^15,b^15) : 0.0f;
    }
  }
  return t;
}
constexpr Tbl TBL = make_tbl();
constexpr int PC[16] = {0,1,1,2,1,2,2,3,1,2,2,3,2,3,3,4};

// y-planes grouped by grade. out[y] += w[pc(y)]*x[y]; odd y: += w[4+pc(y)]*x[y^1]
constexpr int GRADE_Y[5][6] = {{0,0,0,0,0,0},{1,2,4,8,0,0},{3,5,6,9,10,12},{7,11,13,14,0,0},{15,0,0,0,0,0}};
constexpr int GRADE_N[5] = {1,4,6,4,1};

__device__ __forceinline__ u16 f2bf(float f){
  union { float f; unsigned u; } v; v.f = f;
  unsigned r = v.u + 0x7fffu + ((v.u >> 16) & 1u);   // RNE
  return (u16)(r >> 16);
}

// lgkm-only barrier: global_load_lds prefetch stays in flight across it.
#define BARRIER() do {                                          \
  asm volatile("s_waitcnt lgkmcnt(0)" ::: "memory");            \
  __builtin_amdgcn_sched_barrier(0);                            \
  __builtin_amdgcn_s_barrier();                                 \
  __builtin_amdgcn_sched_barrier(0);                            \
} while (0)

// full barrier: additionally waits the staged raw loads (vmcnt).
#define FULLBAR() do {                                          \
  asm volatile("s_waitcnt vmcnt(0) lgkmcnt(0)" ::: "memory");   \
  __builtin_amdgcn_sched_barrier(0);                            \
  __builtin_amdgcn_s_barrier();                                 \
  __builtin_amdgcn_sched_barrier(0);                            \
} while (0)

// =====================================================================
// Kernel: weights fp32 -> bf16 B-fragments
// wb offset: ((t*9+b)*8 + nt*2 + kt)*512 + lane*8 + j
// =====================================================================
__global__ __launch_bounds__(256) void k_wb(const float* __restrict__ wg1,
                                            const float* __restrict__ wg2,
                                            const float* __restrict__ wj1,
                                            const float* __restrict__ wj2,
                                            u16* __restrict__ wb)
{
  const int e = blockIdx.x*256 + threadIdx.x;      // 0 .. 147455
  const int t   = e / 36864;                        // tensor (wave-uniform)
  const int rem = e % 36864;                        // c*576 + i*9 + b
  const int c = rem / 576, r2 = rem % 576, i = r2 / 9, b = r2 % 9;
  const float* wp = (t < 2) ? (t ? wg2 : wg1) : ((t == 2) ? wj1 : wj2);
  const float v = wp[rem];
  const int dst = ((t*9 + b)*8 + (c>>4)*2 + (i>>5))*512
                + (16*((i>>3)&3) + (c&15))*8 + (i&7);
  wb[dst] = f2bf(v);
}

// =====================================================================
// Persistent pipelined kernel, half-tile granularity.
// 512 thr = 8 waves: pair = w>>2 (0:gp 1:jn), nt = w&3.
//
// Register model (validated r4-r8): unified budget 512/(waves/SIMD);
// acc = 128 AGPR irreducible; NO arch state held across phases ->
// prefetch lives in the MEMORY SYSTEM via global_load_lds (0 VGPRs).
// LDS: frag 32 KB + raw 32 KB (half-tile fp32) = 64 KB, 1 block/CU.
//
// raw swizzle (rule #21, both-sides): S(B) = B ^ (((B>>11)&7)<<4).
// LDS dest linear; global SOURCE pre-swizzled; convert READS swizzled.
// Makes convert's per-thread strip reads bank-floor-rate.
// =====================================================================
__global__ __launch_bounds__(512)
void k_pipe(const float* __restrict__ x, const u16* __restrict__ wb,
            const float* __restrict__ ref, float* __restrict__ out,
            int tpb)
{
  __shared__ __align__(16) u16   F[16384];   // 32 KB frag / epilogue scratch
  __shared__ __align__(16) float raw[8192];  // 32 KB raw half-tile

  const int t = threadIdx.x, w = t >> 6, l = t & 63;
  const int pair = w >> 2, nt = w & 3;
  const int t1 = pair*2, t2 = t1 + 1;
  const int tile0 = blockIdx.x * tpb;

  // ---- stage one half-tile (16 pos x 32 i) via global_load_lds ----
  // LDS slot B = (k*8+w)*1024 + l*16 (linear). Content = rawlin[S(B)]
  // where rawlin byte D = pos*2048 + ii*64 + y*4. Source global float:
  // tile*16384 + pos*1024 + h*512 + (D&2047)/4.
  auto stage = [&](int tile, int h) {
    #pragma unroll
    for (int k = 0; k < 4; ++k) {
      const int B = (k*8 + w)*1024 + l*16;
      const int D = B ^ (((B >> 11) & 7) << 4);
      const int pos = D >> 11, r = D & 2047;
      const float* g = x + ((size_t)(tile*16 + pos))*1024 + h*512 + (r >> 2);
      __builtin_amdgcn_global_load_lds(
          (const __attribute__((address_space(1))) void*)g,
          (__attribute__((address_space(3))) void*)((char*)raw + (k*8 + w)*1024),
          16, 0, 0);
    }
  };

  stage(tile0, 0);

  f32x4 acc1[16], acc2[16];

  const int nhalf = 2 * tpb;
  for (int hh = 0; hh < nhalf; ++hh) {
    const int s = hh >> 1, h = hh & 1;
    const int tile = tile0 + s;

    if (h == 0) {
      #pragma unroll
      for (int y = 0; y < 16; ++y) {
        acc1[y] = (f32x4){0.f,0.f,0.f,0.f};
        acc2[y] = (f32x4){0.f,0.f,0.f,0.f};
      }
    }

    FULLBAR();               // raw(hh) landed (all waves); frag/scr free

    // ---- convert: raw (swizzled read) -> frag kt=h planes; waves 0-3 ----
    if (t < 256) {
      const int pp = t & 15, ipp = t >> 4;       // ipp 0..15 (i-pair in half)
      float4 X4[8];
      #pragma unroll
      for (int j = 0; j < 8; ++j) {
        const int Bp = pp*2048 + ipp*128 + 16*(j ^ (pp & 7));
        X4[j] = *(const float4*)((const char*)raw + Bp);
      }
      const float* v = (const float*)X4;          // v[y], v[16+y]
      u32* lw = (u32*)F;
      const int d32 = h*256 + (16*((ipp >> 2) & 3) + pp)*4 + (ipp & 3);
      #pragma unroll
      for (int y = 0; y < 16; ++y)
        lw[y*512 + d32] = (u32)f2bf(v[y]) | ((u32)f2bf(v[16 + y]) << 16);
    }

    BARRIER();               // frag(kt=h) published; raw fully consumed

    if (hh + 1 < nhalf)      // prefetch next half; in flight across MFMA+epi
      stage(tile0 + ((hh + 1) >> 1), (hh + 1) & 1);

    // ---- MFMA for kt=h (grade-grouped wb loads) ----
    #pragma unroll
    for (int g = 0; g < 5; ++g) {
      bf16x8 bg1 = *(const bf16x8*)(wb + ((size_t)((t1*9 + g)*8 + nt*2 + h))*512 + l*8);
      bf16x8 bg2 = *(const bf16x8*)(wb + ((size_t)((t2*9 + g)*8 + nt*2 + h))*512 + l*8);
      bf16x8 be1, be2;
      if (g >= 1) {
        be1 = *(const bf16x8*)(wb + ((size_t)((t1*9 + 4+g)*8 + nt*2 + h))*512 + l*8);
        be2 = *(const bf16x8*)(wb + ((size_t)((t2*9 + 4+g)*8 + nt*2 + h))*512 + l*8);
      }
      #pragma unroll
      for (int yi = 0; yi < GRADE_N[g]; ++yi) {
        const int y = GRADE_Y[g][yi];
        bf16x8 a = *(const bf16x8*)&F[y*1024 + h*512 + l*8];
        acc1[y] = __builtin_amdgcn_mfma_f32_16x16x32_bf16(a, bg1, acc1[y], 0, 0, 0);
        acc2[y] = __builtin_amdgcn_mfma_f32_16x16x32_bf16(a, bg2, acc2[y], 0, 0, 0);
        if (y & 1) {                              // left-e0 map, source y^1
          bf16x8 a2 = *(const bf16x8*)&F[(y^1)*1024 + h*512 + l*8];
          acc1[y] = __builtin_amdgcn_mfma_f32_16x16x32_bf16(a2, be1, acc1[y], 0, 0, 0);
          acc2[y] = __builtin_amdgcn_mfma_f32_16x16x32_bf16(a2, be2, acc2[y], 0, 0, 0);
        }
      }
    }

    if (h == 1) {
      BARRIER();             // all frag reads done -> F reusable as scratch

      // ---- epilogue: bilinear + wave-local LDS transpose + 1KB stores ----
      f32x4* scr = (f32x4*)F;                     // 8 waves x 4 KB, wave-private
      const int pg = l >> 4, c16 = l & 15;

      #pragma unroll
      for (int r = 0; r < 4; ++r) {
        float g1[16], g2[16];
        #pragma unroll
        for (int y = 0; y < 16; ++y) { g1[y] = acc1[y][r]; g2[y] = acc2[y][r]; }
        float o[16];
        #pragma unroll
        for (int k = 0; k < 16; ++k) o[k] = 0.0f;

        if (pair == 0) {
          #pragma unroll
          for (int a = 0; a < 16; ++a)
            #pragma unroll
            for (int b = 0; b < 16; ++b) {
              const float sg = TBL.gp[a][b];
              if (sg != 0.0f) o[a ^ b] += sg * g1[a] * g2[b];
            }
          #pragma unroll
          for (int k = 0; k < 16; ++k) o[k] *= 1e-5f;
        } else {
          const float r15 = ref[(size_t)(tile*16 + pg*4 + r)*16 + 15];
          #pragma unroll
          for (int a = 0; a < 16; ++a)
            #pragma unroll
            for (int b = 0; b < 16; ++b) {
              const float sg = TBL.jn[a][b];
              if (sg != 0.0f) o[a & b] += sg * g1[a] * g2[b];
            }
          #pragma unroll
          for (int k = 0; k < 16; ++k) o[k] *= r15;
        }

        #pragma unroll
        for (int j = 0; j < 4; ++j) {
          const int loc = pg*64 + c16*4 + j;
          const int f4s = loc ^ ((loc >> 3) & 7);
          scr[w*256 + f4s] = (f32x4){o[j*4], o[j*4+1], o[j*4+2], o[j*4+3]};
        }
        asm volatile("s_waitcnt lgkmcnt(0)" ::: "memory");
        __builtin_amdgcn_sched_barrier(0);
        #pragma unroll
        for (int q = 0; q < 4; ++q) {
          const int loc = q*64 + l;
          const int f4s = loc ^ ((loc >> 3) & 7);
          const f32x4 v = scr[w*256 + f4s];
          float4* dst = (float4*)(out + ((size_t)(tile*16 + q*4 + r)*128 + pair*64 + nt*16)*16) + l;
          *dst = make_float4(v[0], v[1], v[2], v[3]);
        }
        asm volatile("s_waitcnt lgkmcnt(0)" ::: "memory");
        __builtin_amdgcn_sched_barrier(0);
      }
    }
  }
}

// =====================================================================
// Fallback: exact-fp32 scalar kernel (used if ws too small / odd shape)
// =====================================================================
#define P_TILE 8
#define I_CHUNK 4

__global__ __launch_bounds__(256) void gbl_fused(
    const float* __restrict__ x, const float* __restrict__ ref,
    const float* __restrict__ wg1, const float* __restrict__ wg2,
    const float* __restrict__ wj1, const float* __restrict__ wj2,
    float* __restrict__ out)
{
  __shared__ float lds_x[P_TILE * 1024];
  __shared__ float lds_w[2 * I_CHUNK * 576];

  const int t    = threadIdx.x;
  const int tile = blockIdx.x >> 1;
  const int tau  = blockIdx.x & 1;
  const float* __restrict__ w1g = tau ? wj1 : wg1;
  const float* __restrict__ w2g = tau ? wj2 : wg2;

  const int c  = t & 63;
  const int ps = t >> 6;

  {
    const float4* __restrict__ gx = (const float4*)(x + (size_t)tile * (P_TILE * 1024));
    float4* lx = (float4*)lds_x;
    #pragma unroll
    for (int k = 0; k < 8; ++k) lx[t + k * 256] = gx[t + k * 256];
  }

  float acc1[2][16], acc2[2][16];
  #pragma unroll
  for (int s = 0; s < 2; ++s)
    #pragma unroll
    for (int y = 0; y < 16; ++y) { acc1[s][y] = 0.0f; acc2[s][y] = 0.0f; }

  for (int i0 = 0; i0 < 64; i0 += I_CHUNK) {
    __syncthreads();
    #pragma unroll
    for (int k = 0; k < 9; ++k) {
      const int e  = t + k * 256;
      const int cc = e / 36;
      const int r  = e % 36;
      const int il = r / 9;
      const int b  = r % 9;
      lds_w[ il            * 576 + cc * 9 + b] = w1g[cc * 576 + i0 * 9 + r];
      lds_w[(I_CHUNK + il) * 576 + cc * 9 + b] = w2g[cc * 576 + i0 * 9 + r];
    }
    __syncthreads();

    #pragma unroll
    for (int il = 0; il < I_CHUNK; ++il) {
      float w1[9], w2[9];
      #pragma unroll
      for (int b = 0; b < 9; ++b) {
        w1[b] = lds_w[ il            * 576 + c * 9 + b];
        w2[b] = lds_w[(I_CHUNK + il) * 576 + c * 9 + b];
      }
      #pragma unroll
      for (int s = 0; s < 2; ++s) {
        const int p = ps + s * 4;
        const float4* xr = (const float4*)&lds_x[p * 1024 + (i0 + il) * 16];
        const float4 xa = xr[0], xb = xr[1], xc4 = xr[2], xd = xr[3];
        const float xv[16] = { xa.x, xa.y, xa.z, xa.w, xb.x, xb.y, xb.z, xb.w,
                               xc4.x, xc4.y, xc4.z, xc4.w, xd.x, xd.y, xd.z, xd.w };
        #pragma unroll
        for (int y = 0; y < 16; ++y) {
          acc1[s][y] += w1[PC[y]] * xv[y];
          acc2[s][y] += w2[PC[y]] * xv[y];
        }
        #pragma unroll
        for (int y = 1; y < 16; y += 2) {
          acc1[s][y] += w1[4 + PC[y]] * xv[y ^ 1];
          acc2[s][y] += w2[4 + PC[y]] * xv[y ^ 1];
        }
      }
    }
  }

  #pragma unroll
  for (int s = 0; s < 2; ++s) {
    const int p = ps + s * 4;
    const size_t pos = (size_t)tile * P_TILE + p;
    float o[16];
    #pragma unroll
    for (int k = 0; k < 16; ++k) o[k] = 0.0f;

    if (tau == 0) {
      #pragma unroll
      for (int a = 0; a < 16; ++a)
        #pragma unroll
        for (int b = 0; b < 16; ++b) {
          const float sg = TBL.gp[a][b];
          if (sg != 0.0f) o[a ^ b] += sg * acc1[s][a] * acc2[s][b];
        }
      #pragma unroll
      for (int k = 0; k < 16; ++k) o[k] *= 1e-5f;
    } else {
      const float r15 = ref[pos * 16 + 15];
      #pragma unroll
      for (int a = 0; a < 16; ++a)
        #pragma unroll
        for (int b = 0; b < 16; ++b) {
          const float sg = TBL.jn[a][b];
          if (sg != 0.0f) o[a & b] += sg * acc1[s][a] * acc2[s][b];
        }
      #pragma unroll
      for (int k = 0; k < 16; ++k) o[k] *= r15;
    }

    float4* po = (float4*)(out + (pos * 128 + (size_t)tau * 64 + c) * 16);
    po[0] = make_float4(o[0],  o[1],  o[2],  o[3]);
    po[1] = make_float4(o[4],  o[5],  o[6],  o[7]);
    po[2] = make_float4(o[8],  o[9],  o[10], o[11]);
    po[3] = make_float4(o[12], o[13], o[14], o[15]);
  }
}

// =====================================================================
extern "C" void kernel_launch(void* const* d_in, const int* in_sizes, int n_in,
                              void* d_out, int out_size, void* d_ws, size_t ws_size,
                              hipStream_t stream) {
  const float* x   = (const float*)d_in[0];
  const float* ref = (const float*)d_in[1];
  const float* wg1 = (const float*)d_in[2];
  const float* wg2 = (const float*)d_in[3];
  const float* wj1 = (const float*)d_in[4];
  const float* wj2 = (const float*)d_in[5];
  float* outp = (float*)d_out;

  const int npos = in_sizes[0] / (64 * 16);     // B*N

  if (ws_size >= 294912 && (npos % 16) == 0) {
    const int tiles = npos / 16;
    int grid, tpb;
    if (tiles % 256 == 0) { grid = 256;   tpb = tiles / 256; }
    else                  { grid = tiles; tpb = 1; }
    u16* wb = (u16*)d_ws;
    k_wb  <<<576, 256, 0, stream>>>(wg1, wg2, wj1, wj2, wb);
    k_pipe<<<grid, 512, 0, stream>>>(x, wb, ref, outp, tpb);
  } else {
    const int grid = (npos / P_TILE) * 2;
    gbl_fused<<<grid, 256, 0, stream>>>(x, ref, wg1, wg2, wj1, wj2, outp);
  }
}

// Round 10
// 70.783 us; speedup vs baseline: 1.9106x; 1.2623x over previous
//
#include <hip/hip_runtime.h>

typedef unsigned short u16;
typedef unsigned int   u32;
typedef __attribute__((ext_vector_type(4))) float f32x4;
typedef __attribute__((ext_vector_type(8))) short bf16x8;

// ---------- compile-time Cl(3,0,1) tables ----------
constexpr int pcf(int x){ int c=0; while(x){ c += x&1; x>>=1; } return c; }
constexpr int signexp(int a,int b){ int s=0; a>>=1; while(a){ s += pcf(a&b); a>>=1; } return s&1; }
constexpr float sgnf(int a,int b){ return signexp(a,b) ? -1.0f : 1.0f; }
constexpr float sDf(int a){ return sgnf(a, a^15); }

struct Tbl {
  float gp[16][16];   // g1[a]*g2[b] -> out[a^b], 0 if e0 overlap
  float jn[16][16];   // j1[a]*j2[b] -> out[a&b], 0 unless a|b==15
};
constexpr Tbl make_tbl(){
  Tbl t{};
  for(int a=0;a<16;a++){
    for(int b=0;b<16;b++){
      t.gp[a][b] = (a & b & 1) ? 0.0f : sgnf(a,b);
      t.jn[a][b] = ((a|b)==15) ? sDf(a)*sDf(b)*sDf(a&b)*sgnf(a^15,b^15) : 0.0f;
    }
  }
  return t;
}
constexpr Tbl TBL = make_tbl();
constexpr int PC[16] = {0,1,1,2,1,2,2,3,1,2,2,3,2,3,3,4};

// y-planes grouped by grade. out[y] += w[pc(y)]*x[y]; odd y: += w[4+pc(y)]*x[y^1]
constexpr int GRADE_Y[5][6] = {{0,0,0,0,0,0},{1,2,4,8,0,0},{3,5,6,9,10,12},{7,11,13,14,0,0},{15,0,0,0,0,0}};
constexpr int GRADE_N[5] = {1,4,6,4,1};

__device__ __forceinline__ u16 f2bf(float f){
  union { float f; unsigned u; } v; v.f = f;
  unsigned r = v.u + 0x7fffu + ((v.u >> 16) & 1u);   // RNE
  return (u16)(r >> 16);
}

// =====================================================================
// Kernel: weights fp32 -> bf16 B-fragments
// wb offset: ((t*9+b)*8 + nt*2 + kt)*512 + lane*8 + j
// =====================================================================
__global__ __launch_bounds__(256) void k_wb(const float* __restrict__ wg1,
                                            const float* __restrict__ wg2,
                                            const float* __restrict__ wj1,
                                            const float* __restrict__ wj2,
                                            u16* __restrict__ wb)
{
  const int e = blockIdx.x*256 + threadIdx.x;      // 0 .. 147455
  const int t   = e / 36864;                        // tensor (wave-uniform)
  const int rem = e % 36864;                        // c*576 + i*9 + b
  const int c = rem / 576, r2 = rem % 576, i = r2 / 9, b = r2 % 9;
  const float* wp = (t < 2) ? (t ? wg2 : wg1) : ((t == 2) ? wj1 : wj2);
  const float v = wp[rem];
  const int dst = ((t*9 + b)*8 + (c>>4)*2 + (i>>5))*512
                + (16*((i>>3)&3) + (c&15))*8 + (i&7);
  wb[dst] = f2bf(v);
}

// =====================================================================
// Half-tile kernel: ONE output pair (gp or jn) of one 16-pos tile per
// 256-thread block (4 waves, wave = 16-channel slice nt).
//
// __launch_bounds__(256, 2): forces total regs/wave <= 256
// (arch 128 + acc 128 AGPR) -> TWO 4-wave blocks co-resident per CU
// with INDEPENDENT barrier domains. Round 8 ran this structure at
// 188 arch regs -> 316/wave -> only ONE block/CU -> phases serialized
// (22 us/tile vs 7.8 us memory floor). The 128-arch allocation is
// spill-free for these exact phases (round 4 evidence: VGPR=128,
// FETCH 38 MB clean, same convert/MFMA/epilogue at 512 thr).
// Block-level overlap replaces all failed register/LDS pipelines
// (rounds 5-7, 9): while block A does MFMA+bilinear VALU, block B
// issues x-loads and drains stores.
// =====================================================================
__global__ __launch_bounds__(256, 2)
void k_half(const float* __restrict__ x, const u16* __restrict__ wb,
            const float* __restrict__ ref, float* __restrict__ out)
{
  __shared__ __align__(16) u16 F[16384];     // 32 KB frag buffer / scratch

  const int t = threadIdx.x, w = t >> 6, l = t & 63;
  const int pair = blockIdx.x & 1;
  const int tile = blockIdx.x >> 1;
  const int nt = w;                          // 16-channel slice
  const int t1 = pair*2, t2 = t1 + 1;        // tensor indices

  // ---- phase 1: x -> bf16 fragment transpose (each thread: 2 i-pairs)
  {
    const int pp  = t & 15;                  // position within tile
    const int ip0 = t >> 4;                  // 0..15
    #pragma unroll
    for (int h = 0; h < 2; ++h) {
      const int ip = ip0 + h*16;             // i-pair (i = 2*ip, 2*ip+1)
      float4 X[8];
      const float4* s4 = (const float4*)(x + ((size_t)(tile*16 + pp))*1024 + ip*32);
      #pragma unroll
      for (int k = 0; k < 8; ++k) X[k] = s4[k];
      const int d32 = h*256 + (16*((ip0 >> 2) & 3) + pp)*4 + (ip0 & 3);
      u32* lw = (u32*)F;
      const float* v = (const float*)X;
      #pragma unroll
      for (int y = 0; y < 16; ++y)
        lw[y*512 + d32] = (u32)f2bf(v[y]) | ((u32)f2bf(v[16 + y]) << 16);
    }
  }

  __syncthreads();                           // fragments published

  // ---- phase 2: MFMA linears (grade-grouped wb loads) ----
  f32x4 acc1[16], acc2[16];
  #pragma unroll
  for (int y = 0; y < 16; ++y) {
    acc1[y] = (f32x4){0.f,0.f,0.f,0.f};
    acc2[y] = (f32x4){0.f,0.f,0.f,0.f};
  }

  #pragma unroll
  for (int g = 0; g < 5; ++g) {
    bf16x8 bg1[2], bg2[2], be1[2], be2[2];
    #pragma unroll
    for (int kt = 0; kt < 2; ++kt) {
      bg1[kt] = *(const bf16x8*)(wb + ((size_t)((t1*9 + g)*8 + nt*2 + kt))*512 + l*8);
      bg2[kt] = *(const bf16x8*)(wb + ((size_t)((t2*9 + g)*8 + nt*2 + kt))*512 + l*8);
    }
    if (g >= 1) {
      #pragma unroll
      for (int kt = 0; kt < 2; ++kt) {
        be1[kt] = *(const bf16x8*)(wb + ((size_t)((t1*9 + 4+g)*8 + nt*2 + kt))*512 + l*8);
        be2[kt] = *(const bf16x8*)(wb + ((size_t)((t2*9 + 4+g)*8 + nt*2 + kt))*512 + l*8);
      }
    }
    #pragma unroll
    for (int yi = 0; yi < GRADE_N[g]; ++yi) {
      const int y = GRADE_Y[g][yi];
      #pragma unroll
      for (int kt = 0; kt < 2; ++kt) {
        bf16x8 a = *(const bf16x8*)&F[y*1024 + kt*512 + l*8];
        acc1[y] = __builtin_amdgcn_mfma_f32_16x16x32_bf16(a, bg1[kt], acc1[y], 0, 0, 0);
        acc2[y] = __builtin_amdgcn_mfma_f32_16x16x32_bf16(a, bg2[kt], acc2[y], 0, 0, 0);
      }
      if (y & 1) {                           // left-e0 map, source plane y^1
        #pragma unroll
        for (int kt = 0; kt < 2; ++kt) {
          bf16x8 a = *(const bf16x8*)&F[(y^1)*1024 + kt*512 + l*8];
          acc1[y] = __builtin_amdgcn_mfma_f32_16x16x32_bf16(a, be1[kt], acc1[y], 0, 0, 0);
          acc2[y] = __builtin_amdgcn_mfma_f32_16x16x32_bf16(a, be2[kt], acc2[y], 0, 0, 0);
        }
      }
    }
  }

  __syncthreads();                           // F reusable as scratch

  // ---- phase 3: bilinear + wave-local LDS transpose + 1KB stores ----
  f32x4* scr = (f32x4*)F;                    // 4 waves x 4 KB, wave-private
  const int pg = l >> 4, c16 = l & 15;

  #pragma unroll
  for (int r = 0; r < 4; ++r) {
    float g1[16], g2[16];
    #pragma unroll
    for (int y = 0; y < 16; ++y) { g1[y] = acc1[y][r]; g2[y] = acc2[y][r]; }
    float o[16];
    #pragma unroll
    for (int k = 0; k < 16; ++k) o[k] = 0.0f;

    if (pair == 0) {
      #pragma unroll
      for (int a = 0; a < 16; ++a)
        #pragma unroll
        for (int b = 0; b < 16; ++b) {
          const float sg = TBL.gp[a][b];
          if (sg != 0.0f) o[a ^ b] += sg * g1[a] * g2[b];
        }
      #pragma unroll
      for (int k = 0; k < 16; ++k) o[k] *= 1e-5f;
    } else {
      const float r15 = ref[(size_t)(tile*16 + pg*4 + r)*16 + 15];
      #pragma unroll
      for (int a = 0; a < 16; ++a)
        #pragma unroll
        for (int b = 0; b < 16; ++b) {
          const float sg = TBL.jn[a][b];
          if (sg != 0.0f) o[a & b] += sg * g1[a] * g2[b];
        }
      #pragma unroll
      for (int k = 0; k < 16; ++k) o[k] *= r15;
    }

    // wave-private swizzled scratch (no cross-wave hazard -> no barrier)
    #pragma unroll
    for (int j = 0; j < 4; ++j) {
      const int loc = pg*64 + c16*4 + j;
      const int f4s = loc ^ ((loc >> 3) & 7);
      scr[w*256 + f4s] = (f32x4){o[j*4], o[j*4+1], o[j*4+2], o[j*4+3]};
    }
    #pragma unroll
    for (int q = 0; q < 4; ++q) {
      const int loc = q*64 + l;
      const int f4s = loc ^ ((loc >> 3) & 7);
      const f32x4 v = scr[w*256 + f4s];
      float4* dst = (float4*)(out + ((size_t)(tile*16 + q*4 + r)*128 + pair*64 + nt*16)*16) + l;
      *dst = make_float4(v[0], v[1], v[2], v[3]);
    }
  }
}

// =====================================================================
// Fallback: exact-fp32 scalar kernel (used if ws too small / odd shape)
// =====================================================================
#define P_TILE 8
#define I_CHUNK 4

__global__ __launch_bounds__(256) void gbl_fused(
    const float* __restrict__ x, const float* __restrict__ ref,
    const float* __restrict__ wg1, const float* __restrict__ wg2,
    const float* __restrict__ wj1, const float* __restrict__ wj2,
    float* __restrict__ out)
{
  __shared__ float lds_x[P_TILE * 1024];
  __shared__ float lds_w[2 * I_CHUNK * 576];

  const int t    = threadIdx.x;
  const int tile = blockIdx.x >> 1;
  const int tau  = blockIdx.x & 1;
  const float* __restrict__ w1g = tau ? wj1 : wg1;
  const float* __restrict__ w2g = tau ? wj2 : wg2;

  const int c  = t & 63;
  const int ps = t >> 6;

  {
    const float4* __restrict__ gx = (const float4*)(x + (size_t)tile * (P_TILE * 1024));
    float4* lx = (float4*)lds_x;
    #pragma unroll
    for (int k = 0; k < 8; ++k) lx[t + k * 256] = gx[t + k * 256];
  }

  float acc1[2][16], acc2[2][16];
  #pragma unroll
  for (int s = 0; s < 2; ++s)
    #pragma unroll
    for (int y = 0; y < 16; ++y) { acc1[s][y] = 0.0f; acc2[s][y] = 0.0f; }

  for (int i0 = 0; i0 < 64; i0 += I_CHUNK) {
    __syncthreads();
    #pragma unroll
    for (int k = 0; k < 9; ++k) {
      const int e  = t + k * 256;
      const int cc = e / 36;
      const int r  = e % 36;
      const int il = r / 9;
      const int b  = r % 9;
      lds_w[ il            * 576 + cc * 9 + b] = w1g[cc * 576 + i0 * 9 + r];
      lds_w[(I_CHUNK + il) * 576 + cc * 9 + b] = w2g[cc * 576 + i0 * 9 + r];
    }
    __syncthreads();

    #pragma unroll
    for (int il = 0; il < I_CHUNK; ++il) {
      float w1[9], w2[9];
      #pragma unroll
      for (int b = 0; b < 9; ++b) {
        w1[b] = lds_w[ il            * 576 + c * 9 + b];
        w2[b] = lds_w[(I_CHUNK + il) * 576 + c * 9 + b];
      }
      #pragma unroll
      for (int s = 0; s < 2; ++s) {
        const int p = ps + s * 4;
        const float4* xr = (const float4*)&lds_x[p * 1024 + (i0 + il) * 16];
        const float4 xa = xr[0], xb = xr[1], xc4 = xr[2], xd = xr[3];
        const float xv[16] = { xa.x, xa.y, xa.z, xa.w, xb.x, xb.y, xb.z, xb.w,
                               xc4.x, xc4.y, xc4.z, xc4.w, xd.x, xd.y, xd.z, xd.w };
        #pragma unroll
        for (int y = 0; y < 16; ++y) {
          acc1[s][y] += w1[PC[y]] * xv[y];
          acc2[s][y] += w2[PC[y]] * xv[y];
        }
        #pragma unroll
        for (int y = 1; y < 16; y += 2) {
          acc1[s][y] += w1[4 + PC[y]] * xv[y ^ 1];
          acc2[s][y] += w2[4 + PC[y]] * xv[y ^ 1];
        }
      }
    }
  }

  #pragma unroll
  for (int s = 0; s < 2; ++s) {
    const int p = ps + s * 4;
    const size_t pos = (size_t)tile * P_TILE + p;
    float o[16];
    #pragma unroll
    for (int k = 0; k < 16; ++k) o[k] = 0.0f;

    if (tau == 0) {
      #pragma unroll
      for (int a = 0; a < 16; ++a)
        #pragma unroll
        for (int b = 0; b < 16; ++b) {
          const float sg = TBL.gp[a][b];
          if (sg != 0.0f) o[a ^ b] += sg * acc1[s][a] * acc2[s][b];
        }
      #pragma unroll
      for (int k = 0; k < 16; ++k) o[k] *= 1e-5f;
    } else {
      const float r15 = ref[pos * 16 + 15];
      #pragma unroll
      for (int a = 0; a < 16; ++a)
        #pragma unroll
        for (int b = 0; b < 16; ++b) {
          const float sg = TBL.jn[a][b];
          if (sg != 0.0f) o[a & b] += sg * acc1[s][a] * acc2[s][b];
        }
      #pragma unroll
      for (int k = 0; k < 16; ++k) o[k] *= r15;
    }

    float4* po = (float4*)(out + (pos * 128 + (size_t)tau * 64 + c) * 16);
    po[0] = make_float4(o[0],  o[1],  o[2],  o[3]);
    po[1] = make_float4(o[4],  o[5],  o[6],  o[7]);
    po[2] = make_float4(o[8],  o[9],  o[10], o[11]);
    po[3] = make_float4(o[12], o[13], o[14], o[15]);
  }
}

// =====================================================================
extern "C" void kernel_launch(void* const* d_in, const int* in_sizes, int n_in,
                              void* d_out, int out_size, void* d_ws, size_t ws_size,
                              hipStream_t stream) {
  const float* x   = (const float*)d_in[0];
  const float* ref = (const float*)d_in[1];
  const float* wg1 = (const float*)d_in[2];
  const float* wg2 = (const float*)d_in[3];
  const float* wj1 = (const float*)d_in[4];
  const float* wj2 = (const float*)d_in[5];
  float* outp = (float*)d_out;

  const int npos = in_sizes[0] / (64 * 16);     // B*N

  if (ws_size >= 294912 && (npos % 16) == 0) {
    u16* wb = (u16*)d_ws;
    k_wb  <<<576, 256, 0, stream>>>(wg1, wg2, wj1, wj2, wb);
    k_half<<<(npos / 16) * 2, 256, 0, stream>>>(x, wb, ref, outp);
  } else {
    const int grid = (npos / P_TILE) * 2;
    gbl_fused<<<grid, 256, 0, stream>>>(x, ref, wg1, wg2, wj1, wj2, outp);
  }
}